// Round 3
// baseline (439.805 us; speedup 1.0000x reference)
//
#include <hip/hip_runtime.h>
#include <math.h>

#define BB 32
#define NN 500
#define GG 500
#define HH 128
#define NHEADS 8
#define DD 16
#define KNB 16
#define GT 8           // g-rows per workgroup in pointer kernel
#define NTILES 63      // ceil(500/8)
#define MCHUNK 25      // mean-reduction chunks per batch
#define MROWS 20       // rows per chunk (25*20 = 500)

// ---------------------------------------------------------------------------
// Kernel 1a: partial sums for graph mean (32*25 blocks) + Wsum add (16 blocks)
// ---------------------------------------------------------------------------
__global__ __launch_bounds__(128) void mean_partial_kernel(
    const float* __restrict__ emb, const float* __restrict__ Wqf,
    const float* __restrict__ Wql, float* __restrict__ partial,
    float* __restrict__ Wsum) {
  int blk = blockIdx.x;
  int tid = threadIdx.x;
  if (blk >= BB * MCHUNK) {  // Wsum = Wqf + Wql, float4, 16 blocks
    int idx = (blk - BB * MCHUNK) * 128 + tid;
    const float4* f4 = (const float4*)Wqf;
    const float4* l4 = (const float4*)Wql;
    float4* s4 = (float4*)Wsum;
    for (int i = idx; i < (HH * HH) / 4; i += 2048) {
      float4 a = f4[i], c = l4[i];
      s4[i] = make_float4(a.x + c.x, a.y + c.y, a.z + c.z, a.w + c.w);
    }
    return;
  }
  int b = blk / MCHUNK;
  int chunk = blk % MCHUNK;
  const float* eb = emb + ((size_t)b * NN + chunk * MROWS) * HH;
  float acc = 0.f;
#pragma unroll
  for (int n = 0; n < MROWS; ++n) acc += eb[n * HH + tid];
  partial[(size_t)blk * HH + tid] = acc;
}

// ---------------------------------------------------------------------------
// Kernel 1b: reduce partials -> mean, project through Wqg -> qgraph (B,H)
// ---------------------------------------------------------------------------
__global__ __launch_bounds__(128) void qgraph_kernel(
    const float* __restrict__ partial, const float* __restrict__ Wqg,
    float* __restrict__ qgraph) {
  int b = blockIdx.x;
  int tid = threadIdx.x;
  __shared__ float meanv[HH];
  const float* p = partial + (size_t)b * MCHUNK * HH;
  float acc = 0.f;
#pragma unroll
  for (int c = 0; c < MCHUNK; ++c) acc += p[c * HH + tid];
  meanv[tid] = acc * (1.0f / NN);
  __syncthreads();
  const float4* wrow = (const float4*)(Wqg + (size_t)tid * HH);
  float s = 0.f;
#pragma unroll
  for (int k = 0; k < HH / 4; ++k) {
    float4 w = wrow[k];
    s += meanv[4 * k] * w.x + meanv[4 * k + 1] * w.y +
         meanv[4 * k + 2] * w.z + meanv[4 * k + 3] * w.w;
  }
  qgraph[b * HH + tid] = s;
}

// ---------------------------------------------------------------------------
// Kernel 2: projection, register-tiled, NO LDS.
// Block = 256 thr = 8 row-groups x 32 col-groups; thread tile 4 rows x 4 cols.
// A row reads are identical across the 32 col-lanes -> L1 broadcast.
// W rows (64 KB total) are L2-resident; each 64B line reused over 4 k4 iters.
//   mode 0: no bias;  mode 1: + bias[b*HH + o] (q_graph);  mode 2: + bias[o]
// ---------------------------------------------------------------------------
__global__ __launch_bounds__(256) void proj_kernel(
    const float* __restrict__ A, const int* __restrict__ gather,
    const float* __restrict__ W, const float* __restrict__ bias,
    float* __restrict__ out, int mode) {
  int tid = threadIdx.x;
  int row0 = blockIdx.x * 32;
  int cg = tid & 31; int c0 = cg * 4;
  int rg = tid >> 5; int r0 = rg * 4;

  const float4* Ar[4];
#pragma unroll
  for (int i = 0; i < 4; ++i) {
    int grow = row0 + r0 + i;
    int arow = grow;
    if (gather) { int bofr = grow / GG; arow = bofr * NN + gather[grow]; }
    Ar[i] = (const float4*)(A + (size_t)arow * HH);
  }
  const float4* Wr[4];
#pragma unroll
  for (int j = 0; j < 4; ++j)
    Wr[j] = (const float4*)(W + (size_t)(c0 + j) * HH);

  float acc[4][4];
#pragma unroll
  for (int i = 0; i < 4; ++i)
#pragma unroll
    for (int j = 0; j < 4; ++j) acc[i][j] = 0.f;

#pragma unroll 2
  for (int k4 = 0; k4 < HH / 4; ++k4) {
    float4 a0 = Ar[0][k4], a1 = Ar[1][k4], a2 = Ar[2][k4], a3 = Ar[3][k4];
    float4 w0 = Wr[0][k4], w1 = Wr[1][k4], w2 = Wr[2][k4], w3 = Wr[3][k4];
    acc[0][0] += a0.x*w0.x + a0.y*w0.y + a0.z*w0.z + a0.w*w0.w;
    acc[0][1] += a0.x*w1.x + a0.y*w1.y + a0.z*w1.z + a0.w*w1.w;
    acc[0][2] += a0.x*w2.x + a0.y*w2.y + a0.z*w2.z + a0.w*w2.w;
    acc[0][3] += a0.x*w3.x + a0.y*w3.y + a0.z*w3.z + a0.w*w3.w;
    acc[1][0] += a1.x*w0.x + a1.y*w0.y + a1.z*w0.z + a1.w*w0.w;
    acc[1][1] += a1.x*w1.x + a1.y*w1.y + a1.z*w1.z + a1.w*w1.w;
    acc[1][2] += a1.x*w2.x + a1.y*w2.y + a1.z*w2.z + a1.w*w2.w;
    acc[1][3] += a1.x*w3.x + a1.y*w3.y + a1.z*w3.z + a1.w*w3.w;
    acc[2][0] += a2.x*w0.x + a2.y*w0.y + a2.z*w0.z + a2.w*w0.w;
    acc[2][1] += a2.x*w1.x + a2.y*w1.y + a2.z*w1.z + a2.w*w1.w;
    acc[2][2] += a2.x*w2.x + a2.y*w2.y + a2.z*w2.z + a2.w*w2.w;
    acc[2][3] += a2.x*w3.x + a2.y*w3.y + a2.z*w3.z + a2.w*w3.w;
    acc[3][0] += a3.x*w0.x + a3.y*w0.y + a3.z*w0.z + a3.w*w0.w;
    acc[3][1] += a3.x*w1.x + a3.y*w1.y + a3.z*w1.z + a3.w*w1.w;
    acc[3][2] += a3.x*w2.x + a3.y*w2.y + a3.z*w2.z + a3.w*w2.w;
    acc[3][3] += a3.x*w3.x + a3.y*w3.y + a3.z*w3.z + a3.w*w3.w;
  }

#pragma unroll
  for (int i = 0; i < 4; ++i) {
    int orow = row0 + r0 + i;
    float b0 = 0.f, b1 = 0.f, b2 = 0.f, b3 = 0.f;
    if (mode == 1) {
      int bofr = orow / GG;
      const float* qg = bias + bofr * HH + c0;
      b0 = qg[0]; b1 = qg[1]; b2 = qg[2]; b3 = qg[3];
    } else if (mode == 2) {
      b0 = bias[c0 + 0]; b1 = bias[c0 + 1]; b2 = bias[c0 + 2]; b3 = bias[c0 + 3];
    }
    float4 o4;
    o4.x = acc[i][0] + b0; o4.y = acc[i][1] + b1;
    o4.z = acc[i][2] + b2; o4.w = acc[i][3] + b3;
    *(float4*)(out + (size_t)orow * HH + c0) = o4;
  }
}

// ---------------------------------------------------------------------------
// Kernel 3: per-(b,g) distances + stable top-16 smallest (one wave per row)
// ---------------------------------------------------------------------------
__global__ __launch_bounds__(256) void topk_kernel(
    const float* __restrict__ coords, const int* __restrict__ last_node,
    const float* __restrict__ mask, int* __restrict__ nbr) {
  int lane = threadIdx.x & 63;
  int wid = threadIdx.x >> 6;
  int row = blockIdx.x * 4 + wid;
  if (row >= BB * GG) return;
  int b = row / GG;
  int last = last_node[row];
  const float* cb = coords + (size_t)b * NN * 2;
  float lx = cb[(size_t)last * 2 + 0];
  float ly = cb[(size_t)last * 2 + 1];
  const float* mrow = mask + (size_t)row * NN;

  float dv[8];
#pragma unroll
  for (int j = 0; j < 8; ++j) {
    int n = lane + j * 64;
    float d = INFINITY;
    if (n < NN) {
      float dx = lx - cb[n * 2];
      float dy = ly - cb[n * 2 + 1];
      d = sqrtf(dx * dx + dy * dy);
      if (mrow[n] == -INFINITY) d = INFINITY;
    }
    dv[j] = d;
  }

  int mine = 0;
  for (int r = 0; r < KNB; ++r) {
    float bv = dv[0]; int bj = 0;
#pragma unroll
    for (int j = 1; j < 8; ++j) {
      if (dv[j] < bv) { bv = dv[j]; bj = j; }
    }
    int bn = lane + bj * 64;
#pragma unroll
    for (int off = 32; off; off >>= 1) {
      float ov = __shfl_xor(bv, off, 64);
      int on = __shfl_xor(bn, off, 64);
      if (ov < bv || (ov == bv && on < bn)) { bv = ov; bn = on; }
    }
    if ((bn & 63) == lane) {
      int jw = bn >> 6;
#pragma unroll
      for (int j = 0; j < 8; ++j)
        if (j == jw) dv[j] = INFINITY;
    }
    if (lane == r) mine = bn;
  }
  if (lane < KNB) nbr[(size_t)row * KNB + lane] = mine;
}

// ---------------------------------------------------------------------------
// Kernel 4: sparse glimpse attention, vectorized loads.
// thread t = (h = t>>4, i = t&15): owns neighbor i of head h.
// Score: K row via 4x float4. V: scale own row by own attn weight, write to
// LDS, then column-sum (conflict-free: stride 132).
// ---------------------------------------------------------------------------
__global__ __launch_bounds__(128) void attn_kernel(
    const float* __restrict__ Q, const float* __restrict__ Kb,
    const float* __restrict__ Vb, const int* __restrict__ nbr,
    float* __restrict__ AO) {
  int row = blockIdx.x;
  int b = row / GG;
  int t = threadIdx.x;
  __shared__ float qs[HH];
  __shared__ int nb[KNB];
  __shared__ float vacc[KNB][HH + 4];   // stride 132: (4i+t)%32 conflict-free
  qs[t] = Q[(size_t)row * HH + t];
  if (t < KNB) nb[t] = nbr[(size_t)row * KNB + t];
  __syncthreads();
  int h = t >> 4;
  int i = t & 15;
  size_t nrow = (size_t)b * NN + nb[i];
  const float4* kr = (const float4*)(Kb + nrow * HH + h * DD);
  const float4* q4 = (const float4*)(qs + h * DD);   // LDS broadcast
  float4 k0 = kr[0], k1 = kr[1], k2 = kr[2], k3 = kr[3];
  float4 qa = q4[0], qb = q4[1], qc = q4[2], qd = q4[3];
  float s = k0.x*qa.x + k0.y*qa.y + k0.z*qa.z + k0.w*qa.w
          + k1.x*qb.x + k1.y*qb.y + k1.z*qb.z + k1.w*qb.w
          + k2.x*qc.x + k2.y*qc.y + k2.z*qc.z + k2.w*qc.w
          + k3.x*qd.x + k3.y*qd.y + k3.z*qd.z + k3.w*qd.w;
  s *= 0.25f;  // 1/sqrt(16)
  float m = s;
#pragma unroll
  for (int off = 8; off; off >>= 1) m = fmaxf(m, __shfl_xor(m, off, 64));
  float e = __expf(s - m);
  float sum = e;
#pragma unroll
  for (int off = 8; off; off >>= 1) sum += __shfl_xor(sum, off, 64);
  float a = e / sum;
  const float4* vr = (const float4*)(Vb + nrow * HH + h * DD);
  float4 v0 = vr[0], v1 = vr[1], v2 = vr[2], v3 = vr[3];
  float4* dst = (float4*)&vacc[i][h * DD];
  dst[0] = make_float4(a*v0.x, a*v0.y, a*v0.z, a*v0.w);
  dst[1] = make_float4(a*v1.x, a*v1.y, a*v1.z, a*v1.w);
  dst[2] = make_float4(a*v2.x, a*v2.y, a*v2.z, a*v2.w);
  dst[3] = make_float4(a*v3.x, a*v3.y, a*v3.z, a*v3.w);
  __syncthreads();
  float o = 0.f;
#pragma unroll
  for (int k = 0; k < KNB; ++k) o += vacc[k][t];
  AO[(size_t)row * HH + t] = o;
}

// ---------------------------------------------------------------------------
// Kernel 5: fused pointer scores + tanh-clip + masked softmax -> probs.
// fq rows are wave-uniform -> scalar/broadcast loads, NO LDS in inner loop.
// tanh(x)*10 = 10 - 20/(exp(2x)+1); exp(t-10+mask), no max reduction needed.
// ---------------------------------------------------------------------------
__global__ __launch_bounds__(256) void pointer_kernel(
    const float* __restrict__ FQ, const float* __restrict__ emb,
    const float* __restrict__ mask, float* __restrict__ out) {
  int tile = blockIdx.x;
  int b = tile / NTILES;
  int g0 = (tile % NTILES) * GT;
  int gc = min(GT, GG - g0);
  int tid = threadIdx.x;

  int n1 = tid;
  int n2 = tid + 256;
  bool v2 = (n2 < NN);
  const float4* e1 = (const float4*)(emb + ((size_t)b * NN + n1) * HH);
  const float4* e2 = (const float4*)(emb + ((size_t)b * NN + (v2 ? n2 : n1)) * HH);
  const float* fq0 = FQ + (size_t)(b * GG + g0) * HH;   // wave-uniform

  float acc1[GT], acc2[GT];
#pragma unroll
  for (int g = 0; g < GT; ++g) { acc1[g] = 0.f; acc2[g] = 0.f; }

#pragma unroll 2
  for (int k4 = 0; k4 < HH / 4; ++k4) {
    float4 a = e1[k4];
    float4 c = e2[k4];
#pragma unroll
    for (int g = 0; g < GT; ++g) {
      int gg = (g < gc) ? g : 0;                 // uniform clamp (tail tile)
      const float* w = fq0 + (size_t)gg * HH + k4 * 4;
      float w0 = w[0], w1 = w[1], w2 = w[2], w3 = w[3];  // s_load/broadcast
      acc1[g] += a.x * w0 + a.y * w1 + a.z * w2 + a.w * w3;
      acc2[g] += c.x * w0 + c.y * w1 + c.z * w2 + c.w * w3;
    }
  }

  float p1[GT], p2[GT];
#pragma unroll
  for (int g = 0; g < GT; ++g) {
    float mk1 = 0.f, mk2 = 0.f;
    if (g < gc) {
      size_t mrow = (size_t)(b * GG + g0 + g) * NN;
      mk1 = mask[mrow + n1];
      mk2 = v2 ? mask[mrow + n2] : 0.f;
    }
    float t1 = 10.f - 20.f / (__expf(2.f * acc1[g]) + 1.f);
    float t2 = 10.f - 20.f / (__expf(2.f * acc2[g]) + 1.f);
    p1[g] = __expf(t1 - 10.f + mk1);
    p2[g] = v2 ? __expf(t2 - 10.f + mk2) : 0.f;
  }

  __shared__ float wsums[4][GT];
  __shared__ float tot[GT];
  int lane = tid & 63;
  int w = tid >> 6;
#pragma unroll
  for (int g = 0; g < GT; ++g) {
    float s = p1[g] + p2[g];
#pragma unroll
    for (int off = 32; off; off >>= 1) s += __shfl_xor(s, off, 64);
    if (lane == 0) wsums[w][g] = s;
  }
  __syncthreads();
  if (tid < GT)
    tot[tid] = wsums[0][tid] + wsums[1][tid] + wsums[2][tid] + wsums[3][tid];
  __syncthreads();

#pragma unroll
  for (int g = 0; g < GT; ++g) {
    if (g < gc) {
      float inv = 1.f / tot[g];
      size_t orow = (size_t)(b * GG + g0 + g) * NN;
      out[orow + n1] = p1[g] * inv;
      if (v2) out[orow + n2] = p2[g] * inv;
    }
  }
}

// ---------------------------------------------------------------------------
extern "C" void kernel_launch(void* const* d_in, const int* in_sizes, int n_in,
                              void* d_out, int out_size, void* d_ws,
                              size_t ws_size, hipStream_t stream) {
  const float* coords    = (const float*)d_in[0];
  const float* emb       = (const float*)d_in[1];
  const int*   last_node = (const int*)d_in[2];
  const float* mask      = (const float*)d_in[3];
  const float* Wqg       = (const float*)d_in[4];
  const float* Wqf       = (const float*)d_in[5];
  const float* Wql       = (const float*)d_in[6];
  const float* Wk        = (const float*)d_in[7];
  const float* Wv        = (const float*)d_in[8];
  const float* Wc        = (const float*)d_in[9];
  const float* bc        = (const float*)d_in[10];

  float* wsf    = (float*)d_ws;
  float* Wsum   = wsf;                       // 128*128
  float* qgraph = Wsum + HH * HH;            // 32*128
  float* Kb     = qgraph + BB * HH;          // 32*500*128
  float* Vb     = Kb + (size_t)BB * NN * HH;
  float* Qb     = Vb + (size_t)BB * NN * HH; // also reused for final_q
  float* AO     = Qb + (size_t)BB * GG * HH;
  int*   nbr    = (int*)(AO + (size_t)BB * GG * HH);
  float* partial = (float*)(nbr + (size_t)BB * GG * KNB);  // 32*25*128

  float* outp   = (float*)d_out;

  mean_partial_kernel<<<BB * MCHUNK + 16, 128, 0, stream>>>(emb, Wqf, Wql,
                                                            partial, Wsum);
  qgraph_kernel<<<BB, 128, 0, stream>>>(partial, Wqg, qgraph);
  proj_kernel<<<500, 256, 0, stream>>>(emb, nullptr, Wk, nullptr, Kb, 0);
  proj_kernel<<<500, 256, 0, stream>>>(emb, nullptr, Wv, nullptr, Vb, 0);
  proj_kernel<<<500, 256, 0, stream>>>(emb, last_node, Wsum, qgraph, Qb, 1);
  topk_kernel<<<4000, 256, 0, stream>>>(coords, last_node, mask, nbr);
  attn_kernel<<<BB * GG, 128, 0, stream>>>(Qb, Kb, Vb, nbr, AO);
  proj_kernel<<<500, 256, 0, stream>>>(AO, nullptr, Wc, bc, Qb, 2);
  pointer_kernel<<<BB * NTILES, 256, 0, stream>>>(Qb, emb, mask, outp);
}

// Round 4
// 377.275 us; speedup vs baseline: 1.1657x; 1.1657x over previous
//
#include <hip/hip_runtime.h>
#include <math.h>

#define BB 32
#define NN 500
#define GG 500
#define HH 128
#define NHEADS 8
#define DD 16
#define KNB 16
#define PGT 8          // g-rows per workgroup in pointer kernel
#define NTILES 63      // ceil(500/8)
#define MCHUNK 25      // mean-reduction chunks per batch
#define MROWS 20       // rows per chunk (25*20 = 500)

// ---------------------------------------------------------------------------
// Kernel 1a: partial sums for graph mean (32*25 blocks) + Wsum add (16 blocks)
// ---------------------------------------------------------------------------
__global__ __launch_bounds__(128) void mean_partial_kernel(
    const float* __restrict__ emb, const float* __restrict__ Wqf,
    const float* __restrict__ Wql, float* __restrict__ partial,
    float* __restrict__ Wsum) {
  int blk = blockIdx.x;
  int tid = threadIdx.x;
  if (blk >= BB * MCHUNK) {
    int idx = (blk - BB * MCHUNK) * 128 + tid;
    const float4* f4 = (const float4*)Wqf;
    const float4* l4 = (const float4*)Wql;
    float4* s4 = (float4*)Wsum;
    for (int i = idx; i < (HH * HH) / 4; i += 2048) {
      float4 a = f4[i], c = l4[i];
      s4[i] = make_float4(a.x + c.x, a.y + c.y, a.z + c.z, a.w + c.w);
    }
    return;
  }
  int b = blk / MCHUNK;
  int chunk = blk % MCHUNK;
  const float* eb = emb + ((size_t)b * NN + chunk * MROWS) * HH;
  float acc = 0.f;
#pragma unroll
  for (int n = 0; n < MROWS; ++n) acc += eb[n * HH + tid];
  partial[(size_t)blk * HH + tid] = acc;
}

// ---------------------------------------------------------------------------
// Kernel 1b: reduce partials -> mean, project through Wqg -> qgraph (B,H)
// ---------------------------------------------------------------------------
__global__ __launch_bounds__(128) void qgraph_kernel(
    const float* __restrict__ partial, const float* __restrict__ Wqg,
    float* __restrict__ qgraph) {
  int b = blockIdx.x;
  int tid = threadIdx.x;
  __shared__ float meanv[HH];
  const float* p = partial + (size_t)b * MCHUNK * HH;
  float acc = 0.f;
#pragma unroll
  for (int c = 0; c < MCHUNK; ++c) acc += p[c * HH + tid];
  meanv[tid] = acc * (1.0f / NN);
  __syncthreads();
  const float4* wrow = (const float4*)(Wqg + (size_t)tid * HH);
  float s = 0.f;
#pragma unroll
  for (int k = 0; k < HH / 4; ++k) {
    float4 w = wrow[k];
    s += meanv[4 * k] * w.x + meanv[4 * k + 1] * w.y +
         meanv[4 * k + 2] * w.z + meanv[4 * k + 3] * w.w;
  }
  qgraph[b * HH + tid] = s;
}

// ---------------------------------------------------------------------------
// Kernel 2: projection. W staged in LDS (coalesced); A rows read from global
// with per-instruction wave-broadcast (32 lanes share one row address).
// Block = 256 thr covers 64 rows x 128 cols; thread tile 8 rows x 4 cols.
// Per k4: 4 ds_read_b128 per 256 VALU-cyc -> VALU-bound (LDS util ~0.75).
//   mode 0: no bias;  mode 1: + bias[b*HH + o] (q_graph);  mode 2: + bias[o]
// ---------------------------------------------------------------------------
__global__ __launch_bounds__(256) void proj_kernel(
    const float* __restrict__ A, const int* __restrict__ gather,
    const float* __restrict__ W, const float* __restrict__ bias,
    float* __restrict__ out, int mode) {
  __shared__ float Ws[32][132];   // [k][col], padded
  int tid = threadIdx.x;
  int cg = tid & 31; int c0 = cg * 4;   // 4 output cols
  int rg = tid >> 5;                    // 8 row-groups
  int row0 = blockIdx.x * 64 + rg * 8;  // this thread's 8 rows

  const float4* Ar[8];
#pragma unroll
  for (int i = 0; i < 8; ++i) {
    int grow = row0 + i;
    int arow = grow;
    if (gather) { int bofr = grow / GG; arow = bofr * NN + gather[grow]; }
    Ar[i] = (const float4*)(A + (size_t)arow * HH);
  }

  float acc[8][4];
#pragma unroll
  for (int i = 0; i < 8; ++i)
#pragma unroll
    for (int j = 0; j < 4; ++j) acc[i][j] = 0.f;

  for (int ks = 0; ks < 4; ++ks) {
    int k0 = ks * 32;
    // stage W slice: 128 cols x 32 k = 1024 float4 / 256 threads
#pragma unroll
    for (int j = 0; j < 4; ++j) {
      int f = tid + j * 256;
      int o = f >> 3; int kq = f & 7;
      float4 w4 = *(const float4*)(W + (size_t)o * HH + k0 + kq * 4);
      Ws[kq * 4 + 0][o] = w4.x;
      Ws[kq * 4 + 1][o] = w4.y;
      Ws[kq * 4 + 2][o] = w4.z;
      Ws[kq * 4 + 3][o] = w4.w;
    }
    __syncthreads();
#pragma unroll
    for (int k4 = 0; k4 < 8; ++k4) {
      float4 a[8];
#pragma unroll
      for (int i = 0; i < 8; ++i) a[i] = Ar[i][ks * 8 + k4];
#pragma unroll
      for (int k = 0; k < 4; ++k) {
        float4 wv = *(const float4*)&Ws[k4 * 4 + k][c0];
#pragma unroll
        for (int i = 0; i < 8; ++i) {
          float av = (k == 0) ? a[i].x : (k == 1) ? a[i].y
                   : (k == 2) ? a[i].z : a[i].w;
          acc[i][0] = fmaf(av, wv.x, acc[i][0]);
          acc[i][1] = fmaf(av, wv.y, acc[i][1]);
          acc[i][2] = fmaf(av, wv.z, acc[i][2]);
          acc[i][3] = fmaf(av, wv.w, acc[i][3]);
        }
      }
    }
    __syncthreads();
  }

#pragma unroll
  for (int i = 0; i < 8; ++i) {
    int orow = row0 + i;
    float b0 = 0.f, b1 = 0.f, b2 = 0.f, b3 = 0.f;
    if (mode == 1) {
      int bofr = orow / GG;
      const float* qg = bias + bofr * HH + c0;
      b0 = qg[0]; b1 = qg[1]; b2 = qg[2]; b3 = qg[3];
    } else if (mode == 2) {
      b0 = bias[c0 + 0]; b1 = bias[c0 + 1]; b2 = bias[c0 + 2]; b3 = bias[c0 + 3];
    }
    float4 o4;
    o4.x = acc[i][0] + b0; o4.y = acc[i][1] + b1;
    o4.z = acc[i][2] + b2; o4.w = acc[i][3] + b3;
    *(float4*)(out + (size_t)orow * HH + c0) = o4;
  }
}

// ---------------------------------------------------------------------------
// Kernel 3: per-(b,g) distances + stable top-16 smallest (one wave per row)
// ---------------------------------------------------------------------------
__global__ __launch_bounds__(256) void topk_kernel(
    const float* __restrict__ coords, const int* __restrict__ last_node,
    const float* __restrict__ mask, int* __restrict__ nbr) {
  int lane = threadIdx.x & 63;
  int wid = threadIdx.x >> 6;
  int row = blockIdx.x * 4 + wid;
  if (row >= BB * GG) return;
  int b = row / GG;
  int last = last_node[row];
  const float* cb = coords + (size_t)b * NN * 2;
  float lx = cb[(size_t)last * 2 + 0];
  float ly = cb[(size_t)last * 2 + 1];
  const float* mrow = mask + (size_t)row * NN;

  float dv[8];
#pragma unroll
  for (int j = 0; j < 8; ++j) {
    int n = lane + j * 64;
    float d = INFINITY;
    if (n < NN) {
      float dx = lx - cb[n * 2];
      float dy = ly - cb[n * 2 + 1];
      d = sqrtf(dx * dx + dy * dy);
      if (mrow[n] == -INFINITY) d = INFINITY;
    }
    dv[j] = d;
  }

  int mine = 0;
  for (int r = 0; r < KNB; ++r) {
    float bv = dv[0]; int bj = 0;
#pragma unroll
    for (int j = 1; j < 8; ++j) {
      if (dv[j] < bv) { bv = dv[j]; bj = j; }
    }
    int bn = lane + bj * 64;
#pragma unroll
    for (int off = 32; off; off >>= 1) {
      float ov = __shfl_xor(bv, off, 64);
      int on = __shfl_xor(bn, off, 64);
      if (ov < bv || (ov == bv && on < bn)) { bv = ov; bn = on; }
    }
    if ((bn & 63) == lane) {
      int jw = bn >> 6;
#pragma unroll
      for (int j = 0; j < 8; ++j)
        if (j == jw) dv[j] = INFINITY;
    }
    if (lane == r) mine = bn;
  }
  if (lane < KNB) nbr[(size_t)row * KNB + lane] = mine;
}

// ---------------------------------------------------------------------------
// Kernel 4: sparse glimpse attention, vectorized loads (as R2).
// ---------------------------------------------------------------------------
__global__ __launch_bounds__(128) void attn_kernel(
    const float* __restrict__ Q, const float* __restrict__ Kb,
    const float* __restrict__ Vb, const int* __restrict__ nbr,
    float* __restrict__ AO) {
  int row = blockIdx.x;
  int b = row / GG;
  int t = threadIdx.x;
  __shared__ float qs[HH];
  __shared__ int nb[KNB];
  __shared__ float vacc[KNB][HH + 4];
  qs[t] = Q[(size_t)row * HH + t];
  if (t < KNB) nb[t] = nbr[(size_t)row * KNB + t];
  __syncthreads();
  int h = t >> 4;
  int i = t & 15;
  size_t nrow = (size_t)b * NN + nb[i];
  const float4* kr = (const float4*)(Kb + nrow * HH + h * DD);
  const float4* q4 = (const float4*)(qs + h * DD);
  float4 k0 = kr[0], k1 = kr[1], k2 = kr[2], k3 = kr[3];
  float4 qa = q4[0], qb = q4[1], qc = q4[2], qd = q4[3];
  float s = k0.x*qa.x + k0.y*qa.y + k0.z*qa.z + k0.w*qa.w
          + k1.x*qb.x + k1.y*qb.y + k1.z*qb.z + k1.w*qb.w
          + k2.x*qc.x + k2.y*qc.y + k2.z*qc.z + k2.w*qc.w
          + k3.x*qd.x + k3.y*qd.y + k3.z*qd.z + k3.w*qd.w;
  s *= 0.25f;
  float m = s;
#pragma unroll
  for (int off = 8; off; off >>= 1) m = fmaxf(m, __shfl_xor(m, off, 64));
  float e = __expf(s - m);
  float sum = e;
#pragma unroll
  for (int off = 8; off; off >>= 1) sum += __shfl_xor(sum, off, 64);
  float a = e / sum;
  const float4* vr = (const float4*)(Vb + nrow * HH + h * DD);
  float4 v0 = vr[0], v1 = vr[1], v2 = vr[2], v3 = vr[3];
  float4* dst = (float4*)&vacc[i][h * DD];
  dst[0] = make_float4(a*v0.x, a*v0.y, a*v0.z, a*v0.w);
  dst[1] = make_float4(a*v1.x, a*v1.y, a*v1.z, a*v1.w);
  dst[2] = make_float4(a*v2.x, a*v2.y, a*v2.z, a*v2.w);
  dst[3] = make_float4(a*v3.x, a*v3.y, a*v3.z, a*v3.w);
  __syncthreads();
  float o = 0.f;
#pragma unroll
  for (int k = 0; k < KNB; ++k) o += vacc[k][t];
  AO[(size_t)row * HH + t] = o;
}

// ---------------------------------------------------------------------------
// Kernel 5: fused pointer scores + tanh-clip + masked softmax -> probs.
// 128 thr/block; thread tile 8 g x 4 n; fq in LDS (uniform-addr broadcast);
// mask prefetched into registers BEFORE the k-loop (overlaps 32MB fetch).
// tanh(x)*10 - 10 = -20/(exp(2x)+1); no max reduction needed.
// ---------------------------------------------------------------------------
__global__ __launch_bounds__(128) void pointer_kernel(
    const float* __restrict__ FQ, const float* __restrict__ emb,
    const float* __restrict__ mask, float* __restrict__ out) {
  int tile = blockIdx.x;
  int b = tile / NTILES;
  int g0 = (tile % NTILES) * PGT;
  int gc = min(PGT, GG - g0);
  int tid = threadIdx.x;

  __shared__ float fq[PGT][HH];
  {
    const float4* src = (const float4*)(FQ + (size_t)(b * GG + g0) * HH);
    float4* dstl = (float4*)fq;
#pragma unroll
    for (int j = 0; j < 2; ++j) {
      int i = tid + j * 128;           // 256 float4 total
      int g = i >> 5;
      dstl[i] = (g < gc) ? src[i] : make_float4(0.f, 0.f, 0.f, 0.f);
    }
  }

  int n0 = tid, n1 = tid + 128, n2 = tid + 256, n3 = tid + 384;
  bool v3 = (n3 < NN);
  const float4* e0 = (const float4*)(emb + ((size_t)b * NN + n0) * HH);
  const float4* e1 = (const float4*)(emb + ((size_t)b * NN + n1) * HH);
  const float4* e2 = (const float4*)(emb + ((size_t)b * NN + n2) * HH);
  const float4* e3 = (const float4*)(emb + ((size_t)b * NN + (v3 ? n3 : n0)) * HH);

  // prefetch mask into registers (independent of k-loop -> overlapped)
  float mk[PGT][4];
#pragma unroll
  for (int g = 0; g < PGT; ++g) {
    if (g < gc) {
      const float* mrow = mask + (size_t)(b * GG + g0 + g) * NN;
      mk[g][0] = mrow[n0];
      mk[g][1] = mrow[n1];
      mk[g][2] = mrow[n2];
      mk[g][3] = v3 ? mrow[n3] : 0.f;
    } else {
      mk[g][0] = mk[g][1] = mk[g][2] = mk[g][3] = 0.f;
    }
  }
  __syncthreads();

  float acc[PGT][4];
#pragma unroll
  for (int g = 0; g < PGT; ++g)
#pragma unroll
    for (int j = 0; j < 4; ++j) acc[g][j] = 0.f;

#pragma unroll 2
  for (int k4 = 0; k4 < HH / 4; ++k4) {
    float4 a0 = e0[k4], a1 = e1[k4], a2 = e2[k4], a3 = e3[k4];
#pragma unroll
    for (int g = 0; g < PGT; ++g) {
      float4 w = *(const float4*)&fq[g][k4 * 4];   // uniform -> broadcast
      acc[g][0] = fmaf(a0.x, w.x, acc[g][0]);
      acc[g][0] = fmaf(a0.y, w.y, acc[g][0]);
      acc[g][0] = fmaf(a0.z, w.z, acc[g][0]);
      acc[g][0] = fmaf(a0.w, w.w, acc[g][0]);
      acc[g][1] = fmaf(a1.x, w.x, acc[g][1]);
      acc[g][1] = fmaf(a1.y, w.y, acc[g][1]);
      acc[g][1] = fmaf(a1.z, w.z, acc[g][1]);
      acc[g][1] = fmaf(a1.w, w.w, acc[g][1]);
      acc[g][2] = fmaf(a2.x, w.x, acc[g][2]);
      acc[g][2] = fmaf(a2.y, w.y, acc[g][2]);
      acc[g][2] = fmaf(a2.z, w.z, acc[g][2]);
      acc[g][2] = fmaf(a2.w, w.w, acc[g][2]);
      acc[g][3] = fmaf(a3.x, w.x, acc[g][3]);
      acc[g][3] = fmaf(a3.y, w.y, acc[g][3]);
      acc[g][3] = fmaf(a3.z, w.z, acc[g][3]);
      acc[g][3] = fmaf(a3.w, w.w, acc[g][3]);
    }
  }

  float p[PGT][4];
#pragma unroll
  for (int g = 0; g < PGT; ++g) {
#pragma unroll
    for (int j = 0; j < 4; ++j) {
      // tanh(x)*10 - 10 = -20/(e^{2x}+1); p = exp(that + mask)
      float t = -20.f / (__expf(2.f * acc[g][j]) + 1.f);
      p[g][j] = __expf(t + mk[g][j]);
    }
    if (!v3) p[g][3] = 0.f;
  }

  // per-g sums: 4-wide local + wave reduce + 2-wave combine
  __shared__ float wred[2][PGT];
  __shared__ float tot[PGT];
  int lane = tid & 63;
  int w = tid >> 6;
#pragma unroll
  for (int g = 0; g < PGT; ++g) {
    float s = p[g][0] + p[g][1] + p[g][2] + p[g][3];
#pragma unroll
    for (int off = 32; off; off >>= 1) s += __shfl_xor(s, off, 64);
    if (lane == 0) wred[w][g] = s;
  }
  __syncthreads();
  if (tid < PGT) tot[tid] = wred[0][tid] + wred[1][tid];
  __syncthreads();

#pragma unroll
  for (int g = 0; g < PGT; ++g) {
    if (g < gc) {
      float inv = 1.f / tot[g];
      size_t orow = (size_t)(b * GG + g0 + g) * NN;
      out[orow + n0] = p[g][0] * inv;
      out[orow + n1] = p[g][1] * inv;
      out[orow + n2] = p[g][2] * inv;
      if (v3) out[orow + n3] = p[g][3] * inv;
    }
  }
}

// ---------------------------------------------------------------------------
extern "C" void kernel_launch(void* const* d_in, const int* in_sizes, int n_in,
                              void* d_out, int out_size, void* d_ws,
                              size_t ws_size, hipStream_t stream) {
  const float* coords    = (const float*)d_in[0];
  const float* emb       = (const float*)d_in[1];
  const int*   last_node = (const int*)d_in[2];
  const float* mask      = (const float*)d_in[3];
  const float* Wqg       = (const float*)d_in[4];
  const float* Wqf       = (const float*)d_in[5];
  const float* Wql       = (const float*)d_in[6];
  const float* Wk        = (const float*)d_in[7];
  const float* Wv        = (const float*)d_in[8];
  const float* Wc        = (const float*)d_in[9];
  const float* bc        = (const float*)d_in[10];

  float* wsf    = (float*)d_ws;
  float* Wsum   = wsf;                       // 128*128
  float* qgraph = Wsum + HH * HH;            // 32*128
  float* Kb     = qgraph + BB * HH;          // 32*500*128
  float* Vb     = Kb + (size_t)BB * NN * HH;
  float* Qb     = Vb + (size_t)BB * NN * HH; // also reused for final_q
  float* AO     = Qb + (size_t)BB * GG * HH;
  int*   nbr    = (int*)(AO + (size_t)BB * GG * HH);
  float* partial = (float*)(nbr + (size_t)BB * GG * KNB);  // 32*25*128

  float* outp   = (float*)d_out;

  mean_partial_kernel<<<BB * MCHUNK + 16, 128, 0, stream>>>(emb, Wqf, Wql,
                                                            partial, Wsum);
  qgraph_kernel<<<BB, 128, 0, stream>>>(partial, Wqg, qgraph);
  proj_kernel<<<250, 256, 0, stream>>>(emb, nullptr, Wk, nullptr, Kb, 0);
  proj_kernel<<<250, 256, 0, stream>>>(emb, nullptr, Wv, nullptr, Vb, 0);
  proj_kernel<<<250, 256, 0, stream>>>(emb, last_node, Wsum, qgraph, Qb, 1);
  topk_kernel<<<4000, 256, 0, stream>>>(coords, last_node, mask, nbr);
  attn_kernel<<<BB * GG, 128, 0, stream>>>(Qb, Kb, Vb, nbr, AO);
  proj_kernel<<<250, 256, 0, stream>>>(AO, nullptr, Wc, bc, Qb, 2);
  pointer_kernel<<<BB * NTILES, 128, 0, stream>>>(Qb, emb, mask, outp);
}

// Round 5
// 266.709 us; speedup vs baseline: 1.6490x; 1.4146x over previous
//
#include <hip/hip_runtime.h>
#include <math.h>

#define BB 32
#define NN 500
#define GG 500
#define HH 128
#define NHEADS 8
#define DD 16
#define KNB 16
#define PGT 16         // g-rows per pointer block
#define PTILES 32      // ceil(500/16)
#define NPAD 512       // embT row length (padded, zero-filled)
#define MCHUNK 25
#define MROWS 20

// ===========================================================================
// Combo kernel 1: independent prep work in one dispatch.
//   blocks [0,800)        : graph-mean partial sums (tid<128)
//   blocks [800,816)      : Wsum = Wq_first + Wq_last (tid<128)
//   blocks [816,4816)     : topk neighbors (256 thr, 4 rows/block)
//   blocks [4816,5840)    : emb -> embT transpose (LDS 32x64 tile)
// ===========================================================================
__global__ __launch_bounds__(256) void combo1_kernel(
    const float* __restrict__ emb, const float* __restrict__ Wqf,
    const float* __restrict__ Wql, const float* __restrict__ coords,
    const int* __restrict__ last_node, const float* __restrict__ mask,
    float* __restrict__ partial, float* __restrict__ Wsum,
    int* __restrict__ nbr, float* __restrict__ embT) {
  __shared__ float tt[32][65];
  int blk = blockIdx.x;
  int tid = threadIdx.x;

  if (blk < 800) {            // ---- mean partials ----
    if (tid < 128) {
      int b = blk / MCHUNK;
      int chunk = blk % MCHUNK;
      const float* eb = emb + ((size_t)b * NN + chunk * MROWS) * HH;
      float acc = 0.f;
#pragma unroll
      for (int n = 0; n < MROWS; ++n) acc += eb[n * HH + tid];
      partial[(size_t)blk * HH + tid] = acc;
    }
    return;
  }
  if (blk < 816) {            // ---- Wsum ----
    if (tid < 128) {
      int idx = (blk - 800) * 128 + tid;
      const float4* f4 = (const float4*)Wqf;
      const float4* l4 = (const float4*)Wql;
      float4* s4 = (float4*)Wsum;
      for (int i = idx; i < (HH * HH) / 4; i += 2048) {
        float4 a = f4[i], c = l4[i];
        s4[i] = make_float4(a.x + c.x, a.y + c.y, a.z + c.z, a.w + c.w);
      }
    }
    return;
  }
  if (blk < 4816) {           // ---- topk ----
    int lane = tid & 63;
    int wid = tid >> 6;
    int row = (blk - 816) * 4 + wid;
    if (row >= BB * GG) return;
    int b = row / GG;
    int last = last_node[row];
    const float* cb = coords + (size_t)b * NN * 2;
    float lx = cb[(size_t)last * 2 + 0];
    float ly = cb[(size_t)last * 2 + 1];
    const float* mrow = mask + (size_t)row * NN;
    float dv[8];
#pragma unroll
    for (int j = 0; j < 8; ++j) {
      int n = lane + j * 64;
      float d = INFINITY;
      if (n < NN) {
        float dx = lx - cb[n * 2];
        float dy = ly - cb[n * 2 + 1];
        d = sqrtf(dx * dx + dy * dy);
        if (mrow[n] == -INFINITY) d = INFINITY;
      }
      dv[j] = d;
    }
    int mine = 0;
    for (int r = 0; r < KNB; ++r) {
      float bv = dv[0]; int bj = 0;
#pragma unroll
      for (int j = 1; j < 8; ++j)
        if (dv[j] < bv) { bv = dv[j]; bj = j; }
      int bn = lane + bj * 64;
#pragma unroll
      for (int off = 32; off; off >>= 1) {
        float ov = __shfl_xor(bv, off, 64);
        int on = __shfl_xor(bn, off, 64);
        if (ov < bv || (ov == bv && on < bn)) { bv = ov; bn = on; }
      }
      if ((bn & 63) == lane) {
        int jw = bn >> 6;
#pragma unroll
        for (int j = 0; j < 8; ++j)
          if (j == jw) dv[j] = INFINITY;
      }
      if (lane == r) mine = bn;
    }
    if (lane < KNB) nbr[(size_t)row * KNB + lane] = mine;
    return;
  }
  // ---- transpose: emb(B,N,H) -> embT(B,H,NPAD), pad n>=500 with 0 ----
  {
    int blkt = blk - 4816;            // 0..1023
    int b = blkt >> 5;
    int t32 = blkt & 31;
    int h0 = (t32 >> 3) * 32;         // 4 h-tiles of 32
    int n0 = (t32 & 7) * 64;          // 8 n-tiles of 64
    int r = tid >> 2;                 // 0..63 (n within tile)
    int c = tid & 3;                  // h-octet 0..3
    int n = n0 + r;
    float4 f0 = make_float4(0.f, 0.f, 0.f, 0.f), f1 = f0;
    if (n < NN) {
      const float* src = emb + ((size_t)b * NN + n) * HH + h0 + c * 8;
      f0 = *(const float4*)(src);
      f1 = *(const float4*)(src + 4);
    }
    tt[c * 8 + 0][r] = f0.x; tt[c * 8 + 1][r] = f0.y;
    tt[c * 8 + 2][r] = f0.z; tt[c * 8 + 3][r] = f0.w;
    tt[c * 8 + 4][r] = f1.x; tt[c * 8 + 5][r] = f1.y;
    tt[c * 8 + 6][r] = f1.z; tt[c * 8 + 7][r] = f1.w;
    __syncthreads();
    int hr = tid >> 3;                // 0..31
    int nc = tid & 7;                 // 0..7 (n-octet)
    float* dst = embT + ((size_t)b * HH + h0 + hr) * NPAD + n0 + nc * 8;
    *(float4*)(dst)     = make_float4(tt[hr][nc*8+0], tt[hr][nc*8+1],
                                      tt[hr][nc*8+2], tt[hr][nc*8+3]);
    *(float4*)(dst + 4) = make_float4(tt[hr][nc*8+4], tt[hr][nc*8+5],
                                      tt[hr][nc*8+6], tt[hr][nc*8+7]);
  }
}

// ---------------------------------------------------------------------------
// Kernel 1b: reduce partials -> mean, project through Wqg -> qgraph (B,H)
// ---------------------------------------------------------------------------
__global__ __launch_bounds__(128) void qgraph_kernel(
    const float* __restrict__ partial, const float* __restrict__ Wqg,
    float* __restrict__ qgraph) {
  int b = blockIdx.x;
  int tid = threadIdx.x;
  __shared__ float meanv[HH];
  const float* p = partial + (size_t)b * MCHUNK * HH;
  float acc = 0.f;
#pragma unroll
  for (int c = 0; c < MCHUNK; ++c) acc += p[c * HH + tid];
  meanv[tid] = acc * (1.0f / NN);
  __syncthreads();
  const float4* wrow = (const float4*)(Wqg + (size_t)tid * HH);
  float s = 0.f;
#pragma unroll
  for (int k = 0; k < HH / 4; ++k) {
    float4 w = wrow[k];
    s += meanv[4 * k] * w.x + meanv[4 * k + 1] * w.y +
         meanv[4 * k + 2] * w.z + meanv[4 * k + 3] * w.w;
  }
  qgraph[b * HH + tid] = s;
}

// ---------------------------------------------------------------------------
// R2-style projection body: A and W both LDS-staged, 4 rows x 4 cols / thread.
// ---------------------------------------------------------------------------
__device__ __forceinline__ void proj_body(
    const float* __restrict__ A, const int* __restrict__ gather,
    const float* __restrict__ W, const float* __restrict__ bias,
    float* __restrict__ out, int mode, int blk,
    float (*As)[36], float (*Ws)[132]) {
  int tid = threadIdx.x;
  int row0 = blk * 32;

  float acc[4][4];
#pragma unroll
  for (int i = 0; i < 4; ++i)
#pragma unroll
    for (int j = 0; j < 4; ++j) acc[i][j] = 0.f;

  int cg = tid & 31; int c0 = cg * 4;
  int rg = tid >> 5; int r0 = rg * 4;

  int sr = tid >> 3;
  int skq = tid & 7;
  int grow = row0 + sr;
  int arow;
  if (gather) {
    int bofr = grow / GG;
    arow = bofr * NN + gather[grow];
  } else {
    arow = grow;
  }
  const float4* Arow4 = (const float4*)(A + (size_t)arow * HH);

  for (int ks = 0; ks < 4; ++ks) {
    int k0 = ks * 32;
    float4 a4 = Arow4[(k0 >> 2) + skq];
    As[skq * 4 + 0][sr] = a4.x;
    As[skq * 4 + 1][sr] = a4.y;
    As[skq * 4 + 2][sr] = a4.z;
    As[skq * 4 + 3][sr] = a4.w;
#pragma unroll
    for (int j = 0; j < 4; ++j) {
      int f = tid + j * 256;
      int o = f >> 3; int kq = f & 7;
      float4 w4 = *(const float4*)(W + (size_t)o * HH + k0 + kq * 4);
      Ws[kq * 4 + 0][o] = w4.x;
      Ws[kq * 4 + 1][o] = w4.y;
      Ws[kq * 4 + 2][o] = w4.z;
      Ws[kq * 4 + 3][o] = w4.w;
    }
    __syncthreads();
#pragma unroll
    for (int k = 0; k < 32; ++k) {
      float4 av = *(const float4*)&As[k][r0];
      float4 wv = *(const float4*)&Ws[k][c0];
      acc[0][0] += av.x*wv.x; acc[0][1] += av.x*wv.y;
      acc[0][2] += av.x*wv.z; acc[0][3] += av.x*wv.w;
      acc[1][0] += av.y*wv.x; acc[1][1] += av.y*wv.y;
      acc[1][2] += av.y*wv.z; acc[1][3] += av.y*wv.w;
      acc[2][0] += av.z*wv.x; acc[2][1] += av.z*wv.y;
      acc[2][2] += av.z*wv.z; acc[2][3] += av.z*wv.w;
      acc[3][0] += av.w*wv.x; acc[3][1] += av.w*wv.y;
      acc[3][2] += av.w*wv.z; acc[3][3] += av.w*wv.w;
    }
    __syncthreads();
  }

#pragma unroll
  for (int i = 0; i < 4; ++i) {
    int orow = row0 + r0 + i;
    float b0 = 0.f, b1 = 0.f, b2 = 0.f, b3 = 0.f;
    if (mode == 1) {
      int bofr = orow / GG;
      const float* qg = bias + bofr * HH + c0;
      b0 = qg[0]; b1 = qg[1]; b2 = qg[2]; b3 = qg[3];
    } else if (mode == 2) {
      b0 = bias[c0 + 0]; b1 = bias[c0 + 1]; b2 = bias[c0 + 2]; b3 = bias[c0 + 3];
    }
    float4 o4;
    o4.x = acc[i][0] + b0; o4.y = acc[i][1] + b1;
    o4.z = acc[i][2] + b2; o4.w = acc[i][3] + b3;
    *(float4*)(out + (size_t)orow * HH + c0) = o4;
  }
}

// seg 0: Kb=emb@Wk ; seg 1: Vb=emb@Wv ; seg 2: Qb=gather(emb)@Wsum + qgraph
// seg 3: FQ=AO@Wc + bc   (launched separately after attn)
__global__ __launch_bounds__(256) void proj_kernel(
    const float* __restrict__ emb, const int* __restrict__ last_node,
    const float* __restrict__ Wk, const float* __restrict__ Wv,
    const float* __restrict__ Wsum, const float* __restrict__ qgraph,
    const float* __restrict__ Wc, const float* __restrict__ bc,
    const float* __restrict__ AO, float* __restrict__ Kb,
    float* __restrict__ Vb, float* __restrict__ Qb, float* __restrict__ FQ,
    int seg_base) {
  __shared__ float As[32][36];
  __shared__ float Ws[32][132];
  int seg = seg_base + blockIdx.x / 500;
  int blk = blockIdx.x % 500;
  if (seg == 0)      proj_body(emb, nullptr,   Wk,   nullptr, Kb, 0, blk, As, Ws);
  else if (seg == 1) proj_body(emb, nullptr,   Wv,   nullptr, Vb, 0, blk, As, Ws);
  else if (seg == 2) proj_body(emb, last_node, Wsum, qgraph,  Qb, 1, blk, As, Ws);
  else               proj_body(AO,  nullptr,   Wc,   bc,      FQ, 2, blk, As, Ws);
}

// ---------------------------------------------------------------------------
// Kernel 4: sparse glimpse attention, vectorized loads.
// ---------------------------------------------------------------------------
__global__ __launch_bounds__(128) void attn_kernel(
    const float* __restrict__ Q, const float* __restrict__ Kb,
    const float* __restrict__ Vb, const int* __restrict__ nbr,
    float* __restrict__ AO) {
  int row = blockIdx.x;
  int b = row / GG;
  int t = threadIdx.x;
  __shared__ float qs[HH];
  __shared__ int nb[KNB];
  __shared__ float vacc[KNB][HH + 4];
  qs[t] = Q[(size_t)row * HH + t];
  if (t < KNB) nb[t] = nbr[(size_t)row * KNB + t];
  __syncthreads();
  int h = t >> 4;
  int i = t & 15;
  size_t nrow = (size_t)b * NN + nb[i];
  const float4* kr = (const float4*)(Kb + nrow * HH + h * DD);
  const float4* q4 = (const float4*)(qs + h * DD);
  float4 k0 = kr[0], k1 = kr[1], k2 = kr[2], k3 = kr[3];
  float4 qa = q4[0], qb = q4[1], qc = q4[2], qd = q4[3];
  float s = k0.x*qa.x + k0.y*qa.y + k0.z*qa.z + k0.w*qa.w
          + k1.x*qb.x + k1.y*qb.y + k1.z*qb.z + k1.w*qb.w
          + k2.x*qc.x + k2.y*qc.y + k2.z*qc.z + k2.w*qc.w
          + k3.x*qd.x + k3.y*qd.y + k3.z*qd.z + k3.w*qd.w;
  s *= 0.25f;
  float m = s;
#pragma unroll
  for (int off = 8; off; off >>= 1) m = fmaxf(m, __shfl_xor(m, off, 64));
  float e = __expf(s - m);
  float sum = e;
#pragma unroll
  for (int off = 8; off; off >>= 1) sum += __shfl_xor(sum, off, 64);
  float a = e / sum;
  const float4* vr = (const float4*)(Vb + nrow * HH + h * DD);
  float4 v0 = vr[0], v1 = vr[1], v2 = vr[2], v3 = vr[3];
  float4* dst = (float4*)&vacc[i][h * DD];
  dst[0] = make_float4(a*v0.x, a*v0.y, a*v0.z, a*v0.w);
  dst[1] = make_float4(a*v1.x, a*v1.y, a*v1.z, a*v1.w);
  dst[2] = make_float4(a*v2.x, a*v2.y, a*v2.z, a*v2.w);
  dst[3] = make_float4(a*v3.x, a*v3.y, a*v3.z, a*v3.w);
  __syncthreads();
  float o = 0.f;
#pragma unroll
  for (int k = 0; k < KNB; ++k) o += vacc[k][t];
  AO[(size_t)row * HH + t] = o;
}

// ---------------------------------------------------------------------------
// Kernel 5: pointer scores via transposed embT -> fully coalesced n-axis.
// Block: (b, 16 g-rows); 128 thr; thread owns n = 4*tid..4*tid+3 (float4)
// and all 16 g accumulators. fq in LDS (wave-uniform b128 broadcast reads).
// 500 = 125*4, so lanes >= 125 are pure padding (embT zero-filled).
// tanh(x)*10 - 10 = -20/(exp(2x)+1); no max reduction needed.
// ---------------------------------------------------------------------------
__global__ __launch_bounds__(128) void pointer_kernel(
    const float* __restrict__ FQ, const float* __restrict__ embT,
    const float* __restrict__ mask, float* __restrict__ out) {
  int tile = blockIdx.x;
  int b = tile / PTILES;
  int g0 = (tile % PTILES) * PGT;
  int gc = min(PGT, GG - g0);
  int tid = threadIdx.x;

  __shared__ float fqs[PGT * HH];
  {
    const float4* src = (const float4*)(FQ + (size_t)(b * GG + g0) * HH);
    float4* dstl = (float4*)fqs;
#pragma unroll
    for (int j = 0; j < 4; ++j) {
      int i = tid + j * 128;            // 512 float4 total
      int g = i >> 5;                   // 32 float4 per row
      dstl[i] = (g < gc) ? src[i] : make_float4(0.f, 0.f, 0.f, 0.f);
    }
  }
  __syncthreads();

  const float4* et = (const float4*)(embT + (size_t)b * HH * NPAD);
  // row h as float4: et[h*128 + tid]

  float4 acc[PGT];
#pragma unroll
  for (int g = 0; g < PGT; ++g) acc[g] = make_float4(0.f, 0.f, 0.f, 0.f);

#pragma unroll 2
  for (int h4 = 0; h4 < HH / 4; ++h4) {
    int h = h4 * 4;
    float4 a0 = et[(h + 0) * (NPAD / 4) + tid];
    float4 a1 = et[(h + 1) * (NPAD / 4) + tid];
    float4 a2 = et[(h + 2) * (NPAD / 4) + tid];
    float4 a3 = et[(h + 3) * (NPAD / 4) + tid];
#pragma unroll
    for (int g = 0; g < PGT; ++g) {
      float4 w = *(const float4*)&fqs[g * HH + h];   // uniform -> broadcast
      acc[g].x = fmaf(a0.x, w.x, acc[g].x);
      acc[g].x = fmaf(a1.x, w.y, acc[g].x);
      acc[g].x = fmaf(a2.x, w.z, acc[g].x);
      acc[g].x = fmaf(a3.x, w.w, acc[g].x);
      acc[g].y = fmaf(a0.y, w.x, acc[g].y);
      acc[g].y = fmaf(a1.y, w.y, acc[g].y);
      acc[g].y = fmaf(a2.y, w.z, acc[g].y);
      acc[g].y = fmaf(a3.y, w.w, acc[g].y);
      acc[g].z = fmaf(a0.z, w.x, acc[g].z);
      acc[g].z = fmaf(a1.z, w.y, acc[g].z);
      acc[g].z = fmaf(a2.z, w.z, acc[g].z);
      acc[g].z = fmaf(a3.z, w.w, acc[g].z);
      acc[g].w = fmaf(a0.w, w.x, acc[g].w);
      acc[g].w = fmaf(a1.w, w.y, acc[g].w);
      acc[g].w = fmaf(a2.w, w.z, acc[g].w);
      acc[g].w = fmaf(a3.w, w.w, acc[g].w);
    }
  }

  // epilogue: tanh-clip + mask + exp (in place), block-sum per g, normalize
  __shared__ float wred[2][PGT];
  __shared__ float tot[PGT];
  int lane = tid & 63;
  int w = tid >> 6;
  bool valid = (tid < 125);             // n = 4*tid < 500

#pragma unroll
  for (int g = 0; g < PGT; ++g) {
    float4 p = make_float4(0.f, 0.f, 0.f, 0.f);
    if (g < gc && valid) {
      const float* mrow = mask + (size_t)(b * GG + g0 + g) * NN;
      float4 m4 = *(const float4*)(mrow + 4 * tid);
      p.x = __expf(-20.f / (__expf(2.f * acc[g].x) + 1.f) + m4.x);
      p.y = __expf(-20.f / (__expf(2.f * acc[g].y) + 1.f) + m4.y);
      p.z = __expf(-20.f / (__expf(2.f * acc[g].z) + 1.f) + m4.z);
      p.w = __expf(-20.f / (__expf(2.f * acc[g].w) + 1.f) + m4.w);
    }
    acc[g] = p;
    float s = p.x + p.y + p.z + p.w;
#pragma unroll
    for (int off = 32; off; off >>= 1) s += __shfl_xor(s, off, 64);
    if (lane == 0) wred[w][g] = s;
  }
  __syncthreads();
  if (tid < PGT) tot[tid] = wred[0][tid] + wred[1][tid];
  __syncthreads();

#pragma unroll
  for (int g = 0; g < PGT; ++g) {
    if (g < gc && valid) {
      float inv = 1.f / tot[g];
      float4 p = acc[g];
      float4 o4 = make_float4(p.x * inv, p.y * inv, p.z * inv, p.w * inv);
      *(float4*)(out + (size_t)(b * GG + g0 + g) * NN + 4 * tid) = o4;
    }
  }
}

// ---------------------------------------------------------------------------
extern "C" void kernel_launch(void* const* d_in, const int* in_sizes, int n_in,
                              void* d_out, int out_size, void* d_ws,
                              size_t ws_size, hipStream_t stream) {
  const float* coords    = (const float*)d_in[0];
  const float* emb       = (const float*)d_in[1];
  const int*   last_node = (const int*)d_in[2];
  const float* mask      = (const float*)d_in[3];
  const float* Wqg       = (const float*)d_in[4];
  const float* Wqf       = (const float*)d_in[5];
  const float* Wql       = (const float*)d_in[6];
  const float* Wk        = (const float*)d_in[7];
  const float* Wv        = (const float*)d_in[8];
  const float* Wc        = (const float*)d_in[9];
  const float* bc        = (const float*)d_in[10];

  float* wsf    = (float*)d_ws;
  float* Wsum   = wsf;                            // 16 K floats
  float* qgraph = Wsum + HH * HH;                 // 4 K
  float* Kb     = qgraph + BB * HH;               // 2.048 M
  float* Vb     = Kb + (size_t)BB * NN * HH;      // 2.048 M
  float* Qb     = Vb + (size_t)BB * NN * HH;      // 2.048 M (reused for FQ)
  float* AO     = Qb + (size_t)BB * GG * HH;      // 2.048 M
  int*   nbr    = (int*)(AO + (size_t)BB * GG * HH);      // 256 K ints
  float* partial = (float*)(nbr + (size_t)BB * GG * KNB); // 102 K
  float* embT   = partial + (size_t)BB * MCHUNK * HH;     // 2.097 M

  float* outp   = (float*)d_out;

  combo1_kernel<<<5840, 256, 0, stream>>>(emb, Wqf, Wql, coords, last_node,
                                          mask, partial, Wsum, nbr, embT);
  qgraph_kernel<<<BB, 128, 0, stream>>>(partial, Wqg, qgraph);
  proj_kernel<<<1500, 256, 0, stream>>>(emb, last_node, Wk, Wv, Wsum, qgraph,
                                        Wc, bc, AO, Kb, Vb, Qb, Qb, 0);
  attn_kernel<<<BB * GG, 128, 0, stream>>>(Qb, Kb, Vb, nbr, AO);
  proj_kernel<<<500, 256, 0, stream>>>(emb, last_node, Wk, Wv, Wsum, qgraph,
                                       Wc, bc, AO, Kb, Vb, Qb, Qb, 3);
  pointer_kernel<<<BB * PTILES, 128, 0, stream>>>(Qb, embT, mask, outp);
}